// Round 9
// baseline (114.701 us; speedup 1.0000x reference)
//
#include <hip/hip_runtime.h>

// Quantum conv circuit, 16 qubits, batch 16.
// Round 9: r8's 3-pass sigma1-factorized structure, with two r8 regressions reverted:
//   - gate/coupling table back in GLOBAL memory (k_setup once; wave-uniform reads -> scalar
//     s_load pipe, zero VALU/LDS cost) instead of per-block double-trig LDS prologue.
//   - LDS drops to 32 KB/block -> 4 blocks/CU; __launch_bounds__(512,8) targets 32 waves/CU.
//   - P1 global store vectorized (s=0/1, s=2/3 are adjacent amps -> float4 stores).
// 512 blocks x 512 threads, 4 amps/thread, 11-bit tiles. st = float2[16][65536] at d_ws;
// tbl (600 floats) at d_ws + 8MB.
// Bit convention: wire w <-> flat-index bit p = 15-w.
// Gate index: L1d0(p)=15-p, L1d1(p)=16+(15-p), L2d0(p)=32+(15-p)/2, L2d1(p)=40+(15-p)/2,
//             L3d0(p)=48+(15-p)/4, L3d1(p)=52+(15-p)/4, L4d0(p)=56+(15-p)/8, L4d1(p)=58+(15-p)/8.

#define DEV __device__ __forceinline__
#define TBL(i) (tbl + (i)*8)

__device__ static const unsigned char G_CP[60] = {
  15,14,13,12,11,10,9,8,7,6,5,4,3,2,1,0,
  15,14,13,12,11,10,9,8,7,6,5,4,3,2,1,0,
  15,13,11,9,7,5,3,1,
  15,13,11,9,7,5,3,1,
  15,11,7,3,
  15,11,7,3,
  15,7,
  15,7
};
__device__ static const unsigned char G_CQ[60] = {
  14,13,12,11,10,9,8,7,6,5,4,3,2,1,0,15,
  14,13,12,11,10,9,8,7,6,5,4,3,2,1,0,15,
  13,11,9,7,5,3,1,15,
  13,11,9,7,5,3,1,15,
  11,7,3,15,
  11,7,3,15,
  7,15,
  7,15
};

DEV float2 F2(float x, float y){ float2 r; r.x = x; r.y = y; return r; }
DEV float2 cmulf(float2 a, float2 b){ return F2(a.x*b.x - a.y*b.y, a.x*b.y + a.y*b.x); }
// XOR bank swizzle on float2 slot index, 2048 slots (32 banks = 16 float2 columns).
DEV int swz(int j){ return j ^ ((j>>4)&15) ^ ((j>>8)&15); }

// slot s (2 bits) -> inner bits A (s bit0), B (s bit1); t's 9 bits fill the rest ascending.
template<int A,int B>
DEV int mapj(int t, int s){
  int j = ((s&1)<<A) | (((s>>1)&1)<<B);
  int ti = 0;
  #pragma unroll
  for (int b=0;b<11;b++){
    if (b!=A && b!=B){ j |= ((t>>ti)&1)<<b; ti++; }
  }
  return j;
}

// 2x2 unitary on slot bit SB of a[4]. g is wave-uniform global -> scalar loads.
template<int SB>
DEV void gate4(float2* a, const float* __restrict__ g){
  float u00r=g[0],u00i=g[1],u01r=g[2],u01i=g[3],u10r=g[4],u10i=g[5],u11r=g[6],u11i=g[7];
  #pragma unroll
  for (int m=0;m<2;m++){
    int i0 = (SB==0) ? (m<<1) : m;
    int i1 = i0 | (1<<SB);
    float2 x0=a[i0], x1=a[i1];
    a[i0] = F2(u00r*x0.x - u00i*x0.y + u01r*x1.x - u01i*x1.y,
               u00r*x0.y + u00i*x0.x + u01r*x1.y + u01i*x1.x);
    a[i1] = F2(u10r*x0.x - u10i*x0.y + u11r*x1.x - u11i*x1.y,
               u10r*x0.y + u10i*x0.x + u11r*x1.y + u11i*x1.x);
  }
}

// RZZ round, couplings [C0,C0+N). Ib = global 16-bit index with the two reg bits zeroed.
template<int C0,int N,unsigned M0,unsigned M1>
DEV void diag4(float2* a, const float* __restrict__ tbl, unsigned Ib){
  const unsigned regmask = M0|M1;
  float2 F0 = F2(1.f, 0.f);
  #pragma unroll
  for (int k=0;k<N;k++){
    const int p = G_CP[C0+k], q = G_CQ[C0+k];
    if ( !(((1u<<p)|(1u<<q)) & regmask) ){
      float c = tbl[480 + 2*(C0+k)], s = tbl[481 + 2*(C0+k)];
      unsigned x = ((Ib>>p) ^ (Ib>>q)) & 1u;
      F0 = cmulf(F0, F2(c, x ? s : -s));
    }
  }
  #pragma unroll
  for (int r=0;r<4;r++){
    unsigned Ir = Ib ^ ((r&1)?M0:0u) ^ ((r&2)?M1:0u);
    float2 ph = F0;
    #pragma unroll
    for (int k=0;k<N;k++){
      const int p = G_CP[C0+k], q = G_CQ[C0+k];
      if ( ((1u<<p)|(1u<<q)) & regmask ){
        float c = tbl[480 + 2*(C0+k)], s = tbl[481 + 2*(C0+k)];
        unsigned x = ((Ir>>p) ^ (Ir>>q)) & 1u;
        ph = cmulf(ph, F2(c, x ? s : -s));
      }
    }
    a[r] = cmulf(a[r], ph);
  }
}

// ---- global index maps ----
DEV unsigned Ia(int j, int o){ return (unsigned)(j | (o<<11)); }
DEV unsigned Ib2(int j, int o){ return (unsigned)((j&63) | (o<<6) | ((j>>6)<<11)); }
DEV unsigned Ic(int j, int o){
  return (unsigned)( ((j&1)<<1) | (((j>>1)&1)<<3) | (((j>>2)&1)<<5)
       | (((j>>3)&63)<<6) | (((j>>9)&1)<<13) | (((j>>10)&1)<<15)
       | (o&1) | (((o>>1)&1)<<2) | (((o>>2)&1)<<4) | (((o>>3)&1)<<12) | (((o>>4)&1)<<14) );
}
// sigma1b on global index (controls 15,13,5,3,1 -> targets 14,12,4,2,0); XOR-linear involution.
DEV unsigned s1b(unsigned I){ return I ^ ((I & 0xA02Au) >> 1); }
// sigma1a folded into LDS read (j-space): (j8->j7)=(g11->g10), (j6->j5)=(g9->g8), (j4->j3)=(g7->g6)
DEV int s1aperm(int j){ return j ^ (((j>>8)&1)<<7) ^ (((j>>6)&1)<<5) ^ (((j>>4)&1)<<3); }
// sigma2 remainder: (g11->g9),(g7->g5),(g3->g1) = (j8->j6),(j4->j2),(j1->j0)
DEV int s2perm(int j){ return j ^ (((j>>8)&1)<<6) ^ (((j>>4)&1)<<2) ^ (((j>>1)&1)<<0); }
// sigma3: (g15->g11),(g7->g3) = (j10->j8),(j4->j1)
DEV int s3perm(int j){ return j ^ (((j>>10)&1)<<8) ^ (((j>>4)&1)<<1); }

// ---------- setup: U = RX(t2)*RZ(t1)*RX(t0) in double + couplings; zero out ----------
__global__ void k_setup(const float* __restrict__ p0, const float* __restrict__ p1,
                        const float* __restrict__ p2, const float* __restrict__ p3,
                        float* __restrict__ tbl, float* __restrict__ out){
  int g = threadIdx.x;
  if (g < 16) out[g] = 0.f;
  if (g >= 60) return;
  int d, j, n; const float* P;
  if (g < 32)      { n=16; d=(g>>4)&1; j=g&15; P=p0; }
  else if (g < 48) { n=8;  d=(g>>3)&1; j=g&7;  P=p1; }
  else if (g < 56) { n=4;  d=(g>>2)&1; j=g&3;  P=p2; }
  else             { n=2;  d=(g>>1)&1; j=g&1;  P=p3; }
  int base = 4*j + 4*n*d;
  double th0 = P[base+0], th1 = P[base+1], th2 = P[base+2], th3 = P[base+3];
  double c0 = cos(th0*0.5), s0 = sin(th0*0.5);
  double ca = cos(th1*0.5), sa = sin(th1*0.5);
  double c2 = cos(th2*0.5), s2 = sin(th2*0.5);
  double B00r =  ca*c0, B00i = -sa*c0;
  double B01r = -sa*s0, B01i = -ca*s0;
  double B10r =  sa*s0, B10i = -ca*s0;
  double B11r =  ca*c0, B11i =  sa*c0;
  float* o = tbl + g*8;
  o[0]=(float)(c2*B00r + s2*B10i); o[1]=(float)(c2*B00i - s2*B10r);
  o[2]=(float)(c2*B01r + s2*B11i); o[3]=(float)(c2*B01i - s2*B11r);
  o[4]=(float)(s2*B00i + c2*B10r); o[5]=(float)(-s2*B00r + c2*B10i);
  o[6]=(float)(s2*B01i + c2*B11r); o[7]=(float)(-s2*B01r + c2*B11i);
  tbl[480 + 2*g] = (float)cos(th3*0.5);
  tbl[481 + 2*g] = (float)sin(th3*0.5);
}

// ======== pass 1: L1d0 g0..g10. inner = g0..10, outer = g11..15 ========
__global__ __launch_bounds__(512, 8)
void k_p1(const float* __restrict__ xre, const float* __restrict__ xim,
          const float* __restrict__ tbl, float2* __restrict__ st){
  const int t = threadIdx.x;
  const int batch = blockIdx.x >> 5, o = blockIdx.x & 31;
  const unsigned hi = ((unsigned)batch<<16) | ((unsigned)o<<11);
  __shared__ float2 lds[2][2048];
  float2 a[4];
  { // S1: map(0,1); j = s | (t<<2): float4 loads
    unsigned base = hi | ((unsigned)t<<2);
    float4 re = *(const float4*)(xre + base);
    float4 im = *(const float4*)(xim + base);
    a[0]=F2(re.x,im.x); a[1]=F2(re.y,im.y); a[2]=F2(re.z,im.z); a[3]=F2(re.w,im.w);
  }
  gate4<0>(a, TBL(15)); gate4<1>(a, TBL(14));                   // g0,g1
  #pragma unroll
  for (int s=0;s<4;s++) lds[0][swz(mapj<0,1>(t,s))] = a[s];
  __syncthreads();
  #pragma unroll
  for (int s=0;s<4;s++) a[s] = lds[0][swz(mapj<2,3>(t,s))];
  gate4<0>(a, TBL(13)); gate4<1>(a, TBL(12));                   // g2,g3
  #pragma unroll
  for (int s=0;s<4;s++) lds[1][swz(mapj<2,3>(t,s))] = a[s];
  __syncthreads();
  #pragma unroll
  for (int s=0;s<4;s++) a[s] = lds[1][swz(mapj<4,5>(t,s))];
  gate4<0>(a, TBL(11)); gate4<1>(a, TBL(10));                   // g4,g5
  #pragma unroll
  for (int s=0;s<4;s++) lds[0][swz(mapj<4,5>(t,s))] = a[s];
  __syncthreads();
  #pragma unroll
  for (int s=0;s<4;s++) a[s] = lds[0][swz(mapj<6,7>(t,s))];
  gate4<0>(a, TBL(9)); gate4<1>(a, TBL(8));                     // g6,g7
  #pragma unroll
  for (int s=0;s<4;s++) lds[1][swz(mapj<6,7>(t,s))] = a[s];
  __syncthreads();
  #pragma unroll
  for (int s=0;s<4;s++) a[s] = lds[1][swz(mapj<8,9>(t,s))];
  gate4<0>(a, TBL(7)); gate4<1>(a, TBL(6));                     // g8,g9
  #pragma unroll
  for (int s=0;s<4;s++) lds[0][swz(mapj<8,9>(t,s))] = a[s];
  __syncthreads();
  #pragma unroll
  for (int s=0;s<4;s++) a[s] = lds[0][swz(mapj<0,10>(t,s))];
  gate4<1>(a, TBL(5));                                          // g10 (slot bit 1)
  { // store: mapj<0,10>(t,s): s=0,1 adjacent; s=2,3 adjacent at +1024 -> two float4s
    unsigned jb = hi | ((unsigned)t<<1);
    float4 v0; v0.x=a[0].x; v0.y=a[0].y; v0.z=a[1].x; v0.w=a[1].y;
    float4 v1; v1.x=a[2].x; v1.y=a[2].y; v1.z=a[3].x; v1.w=a[3].y;
    *(float4*)(st + jb) = v0;
    *(float4*)(st + jb + 1024) = v1;
  }
}

// ======== pass 2: L1d0 g11..15, D0, L1d1 {g0..g5, g11..15}. outer = g6..g10 ========
__global__ __launch_bounds__(512, 8)
void k_p2(const float* __restrict__ tbl, float2* __restrict__ st){
  const int t = threadIdx.x;
  const int batch = blockIdx.x >> 5, o = blockIdx.x & 31;
  const unsigned bb = (unsigned)batch<<16;
  __shared__ float2 lds[2][2048];
  float2 a[4];
  // U1: map(10,9) = (g15,g14)
  #pragma unroll
  for (int s=0;s<4;s++) a[s] = st[bb | Ib2(mapj<10,9>(t,s), o)];
  gate4<0>(a, TBL(0)); gate4<1>(a, TBL(1));                     // L1d0 g15,g14
  #pragma unroll
  for (int s=0;s<4;s++) lds[0][swz(mapj<10,9>(t,s))] = a[s];
  __syncthreads();
  // U2: map(8,7) = (g13,g12)
  #pragma unroll
  for (int s=0;s<4;s++) a[s] = lds[0][swz(mapj<8,7>(t,s))];
  gate4<0>(a, TBL(2)); gate4<1>(a, TBL(3));                     // L1d0 g13,g12
  #pragma unroll
  for (int s=0;s<4;s++) lds[1][swz(mapj<8,7>(t,s))] = a[s];
  __syncthreads();
  // U3: map(6,5) = (g11,g5)
  #pragma unroll
  for (int s=0;s<4;s++) a[s] = lds[1][swz(mapj<6,5>(t,s))];
  gate4<0>(a, TBL(4));                                          // L1d0 g11 -> L1d0 done
  diag4<0,16, (1u<<11),(1u<<5)>(a, tbl, Ib2(mapj<6,5>(t,0), o));// D0
  gate4<0>(a, TBL(20)); gate4<1>(a, TBL(26));                   // L1d1 g11, g5
  #pragma unroll
  for (int s=0;s<4;s++) lds[0][swz(mapj<6,5>(t,s))] = a[s];
  __syncthreads();
  // U4: map(7,8) = (g12,g13)
  #pragma unroll
  for (int s=0;s<4;s++) a[s] = lds[0][swz(mapj<7,8>(t,s))];
  gate4<0>(a, TBL(19)); gate4<1>(a, TBL(18));                   // L1d1 g12,g13
  #pragma unroll
  for (int s=0;s<4;s++) lds[1][swz(mapj<7,8>(t,s))] = a[s];
  __syncthreads();
  // U5: map(9,10) = (g14,g15)
  #pragma unroll
  for (int s=0;s<4;s++) a[s] = lds[1][swz(mapj<9,10>(t,s))];
  gate4<0>(a, TBL(17)); gate4<1>(a, TBL(16));                   // L1d1 g14,g15
  #pragma unroll
  for (int s=0;s<4;s++) lds[0][swz(mapj<9,10>(t,s))] = a[s];
  __syncthreads();
  // U6: map(0,1) = (g0,g1)
  #pragma unroll
  for (int s=0;s<4;s++) a[s] = lds[0][swz(mapj<0,1>(t,s))];
  gate4<0>(a, TBL(31)); gate4<1>(a, TBL(30));                   // L1d1 g0,g1
  #pragma unroll
  for (int s=0;s<4;s++) lds[1][swz(mapj<0,1>(t,s))] = a[s];
  __syncthreads();
  // U7: map(2,3) = (g2,g3)
  #pragma unroll
  for (int s=0;s<4;s++) a[s] = lds[1][swz(mapj<2,3>(t,s))];
  gate4<0>(a, TBL(29)); gate4<1>(a, TBL(28));                   // L1d1 g2,g3
  #pragma unroll
  for (int s=0;s<4;s++) lds[0][swz(mapj<2,3>(t,s))] = a[s];
  __syncthreads();
  // U8: map(4,10) = (g4, spare)
  #pragma unroll
  for (int s=0;s<4;s++) a[s] = lds[0][swz(mapj<4,10>(t,s))];
  gate4<0>(a, TBL(27));                                         // L1d1 g4
  #pragma unroll
  for (int s=0;s<4;s++) st[bb | Ib2(mapj<4,10>(t,s), o)] = a[s];
}

// ======== pass 4: s1b-gather, L1d1 g6..10, D1, s1a, L2..L4, measure ========
// inner j0..10 -> g{1,3,5,6,7,8,9,10,11,13,15}; outer o0..4 -> g{0,2,4,12,14}
__global__ __launch_bounds__(512, 8)
void k_p4(const float* __restrict__ tbl, float2* __restrict__ st, float* __restrict__ out){
  const int t = threadIdx.x;
  const int batch = blockIdx.x >> 5, o = blockIdx.x & 31;
  const unsigned bb = (unsigned)batch<<16;
  __shared__ float2 lds[2][2048];
  __shared__ float red[8];
  float2 a[4];
  // S1: gather via s1b; regs (j3,j4) = (g6,g7)
  #pragma unroll
  for (int s=0;s<4;s++) a[s] = st[bb | s1b(Ic(mapj<3,4>(t,s), o))];
  gate4<0>(a, TBL(25)); gate4<1>(a, TBL(24));                   // L1d1 g6,g7
  #pragma unroll
  for (int s=0;s<4;s++) lds[0][swz(mapj<3,4>(t,s))] = a[s];
  __syncthreads();
  // S2: regs (j5,j6) = (g8,g9)
  #pragma unroll
  for (int s=0;s<4;s++) a[s] = lds[0][swz(mapj<5,6>(t,s))];
  gate4<0>(a, TBL(23)); gate4<1>(a, TBL(22));                   // L1d1 g8,g9
  #pragma unroll
  for (int s=0;s<4;s++) lds[1][swz(mapj<5,6>(t,s))] = a[s];
  __syncthreads();
  // S3: regs (j7,j8) = (g10,g11)
  #pragma unroll
  for (int s=0;s<4;s++) a[s] = lds[1][swz(mapj<7,8>(t,s))];
  gate4<0>(a, TBL(21));                                         // L1d1 g10 -> L1d1 done
  diag4<16,16, (1u<<10),(1u<<11)>(a, tbl, s1b(Ic(mapj<7,8>(t,0), o))); // D1 at pre-sigma1 index
  #pragma unroll
  for (int s=0;s<4;s++) lds[0][swz(mapj<7,8>(t,s))] = a[s];
  __syncthreads();
  // S4: regs (j10,j9) = (g15,g13); s1a folded into read -> full sigma1 now applied
  #pragma unroll
  for (int s=0;s<4;s++) a[s] = lds[0][swz(s1aperm(mapj<10,9>(t,s)))];
  gate4<0>(a, TBL(32)); gate4<1>(a, TBL(33));                   // L2d0 g15,g13
  #pragma unroll
  for (int s=0;s<4;s++) lds[1][swz(mapj<10,9>(t,s))] = a[s];
  __syncthreads();
  // S5: regs (j8,j6) = (g11,g9)
  #pragma unroll
  for (int s=0;s<4;s++) a[s] = lds[1][swz(mapj<8,6>(t,s))];
  gate4<0>(a, TBL(34)); gate4<1>(a, TBL(35));                   // L2d0 g11,g9
  #pragma unroll
  for (int s=0;s<4;s++) lds[0][swz(mapj<8,6>(t,s))] = a[s];
  __syncthreads();
  // S6: regs (j4,j2) = (g7,g5)
  #pragma unroll
  for (int s=0;s<4;s++) a[s] = lds[0][swz(mapj<4,2>(t,s))];
  gate4<0>(a, TBL(36)); gate4<1>(a, TBL(37));                   // L2d0 g7,g5
  #pragma unroll
  for (int s=0;s<4;s++) lds[1][swz(mapj<4,2>(t,s))] = a[s];
  __syncthreads();
  // S7: regs (j1,j0) = (g3,g1)
  #pragma unroll
  for (int s=0;s<4;s++) a[s] = lds[1][swz(mapj<1,0>(t,s))];
  gate4<0>(a, TBL(38)); gate4<1>(a, TBL(39));                   // L2d0 g3,g1 -> L2d0 done
  diag4<32,8, (1u<<3),(1u<<1)>(a, tbl, Ic(mapj<1,0>(t,0), o));  // D2_0
  gate4<0>(a, TBL(46)); gate4<1>(a, TBL(47));                   // L2d1 g3,g1
  #pragma unroll
  for (int s=0;s<4;s++) lds[0][swz(mapj<1,0>(t,s))] = a[s];
  __syncthreads();
  // S8: regs (j2,j4) = (g5,g7)
  #pragma unroll
  for (int s=0;s<4;s++) a[s] = lds[0][swz(mapj<2,4>(t,s))];
  gate4<0>(a, TBL(45)); gate4<1>(a, TBL(44));                   // L2d1 g5,g7
  #pragma unroll
  for (int s=0;s<4;s++) lds[1][swz(mapj<2,4>(t,s))] = a[s];
  __syncthreads();
  // S9: regs (j6,j8) = (g9,g11)
  #pragma unroll
  for (int s=0;s<4;s++) a[s] = lds[1][swz(mapj<6,8>(t,s))];
  gate4<0>(a, TBL(43)); gate4<1>(a, TBL(42));                   // L2d1 g9,g11
  #pragma unroll
  for (int s=0;s<4;s++) lds[0][swz(mapj<6,8>(t,s))] = a[s];
  __syncthreads();
  // S10: regs (j9,j10) = (g13,g15)
  #pragma unroll
  for (int s=0;s<4;s++) a[s] = lds[0][swz(mapj<9,10>(t,s))];
  gate4<0>(a, TBL(41)); gate4<1>(a, TBL(40));                   // L2d1 g13,g15 -> done
  diag4<40,8, (1u<<13),(1u<<15)>(a, tbl, Ic(mapj<9,10>(t,0), o)); // D2_1
  { float2 tmp=a[2]; a[2]=a[3]; a[3]=tmp; }                     // sigma2: CNOT(g15->g13)
  gate4<1>(a, TBL(48));                                         // L3d0 g15
  #pragma unroll
  for (int s=0;s<4;s++) lds[1][swz(mapj<9,10>(t,s))] = a[s];
  __syncthreads();
  // S11: regs (j8,j4) = (g11,g7); sigma2 remainder folded into read
  #pragma unroll
  for (int s=0;s<4;s++) a[s] = lds[1][swz(s2perm(mapj<8,4>(t,s)))];
  gate4<0>(a, TBL(49)); gate4<1>(a, TBL(50));                   // L3d0 g11,g7
  #pragma unroll
  for (int s=0;s<4;s++) lds[0][swz(mapj<8,4>(t,s))] = a[s];
  __syncthreads();
  // S12: regs (j1,j10) = (g3,g15)
  #pragma unroll
  for (int s=0;s<4;s++) a[s] = lds[0][swz(mapj<1,10>(t,s))];
  gate4<0>(a, TBL(51));                                         // L3d0 g3 -> L3d0 done
  diag4<48,4, (1u<<3),(1u<<15)>(a, tbl, Ic(mapj<1,10>(t,0), o)); // D3_0
  gate4<0>(a, TBL(55)); gate4<1>(a, TBL(52));                   // L3d1 g3,g15
  #pragma unroll
  for (int s=0;s<4;s++) lds[1][swz(mapj<1,10>(t,s))] = a[s];
  __syncthreads();
  // S13: regs (j4,j8) = (g7,g11)
  #pragma unroll
  for (int s=0;s<4;s++) a[s] = lds[1][swz(mapj<4,8>(t,s))];
  gate4<0>(a, TBL(54)); gate4<1>(a, TBL(53));                   // L3d1 g7,g11 -> done
  diag4<52,4, (1u<<7),(1u<<11)>(a, tbl, Ic(mapj<4,8>(t,0), o)); // D3_1
  #pragma unroll
  for (int s=0;s<4;s++) lds[0][swz(mapj<4,8>(t,s))] = a[s];
  __syncthreads();
  // S14: regs (j4,j10) = (g7,g15); sigma3 folded into read
  #pragma unroll
  for (int s=0;s<4;s++) a[s] = lds[0][swz(s3perm(mapj<4,10>(t,s)))];
  gate4<0>(a, TBL(57)); gate4<1>(a, TBL(56));                   // L4d0 g7,g15
  diag4<56,2, (1u<<7),(1u<<15)>(a, tbl, Ic(mapj<4,10>(t,0), o)); // D4_0
  gate4<1>(a, TBL(58));                                         // L4d1 g15
  // sigma4, D4_1, L4d1(g7) dropped: invariant for the g15 marginal.
  float s = 0.f;
  #pragma unroll
  for (int r=0;r<4;r++){
    float w = a[r].x*a[r].x + a[r].y*a[r].y;
    s += (r & 2) ? -w : w;
  }
  #pragma unroll
  for (int off=32; off>0; off>>=1) s += __shfl_down(s, off);
  if ((t & 63) == 0) red[t>>6] = s;
  __syncthreads();
  if (t == 0){
    float tot = 0.f;
    #pragma unroll
    for (int w=0; w<8; w++) tot += red[w];
    atomicAdd(out + batch, tot);
  }
}

extern "C" void kernel_launch(void* const* d_in, const int* in_sizes, int n_in,
                              void* d_out, int out_size, void* d_ws, size_t ws_size,
                              hipStream_t stream) {
  const float* xre = (const float*)d_in[0];
  const float* xim = (const float*)d_in[1];
  const float* p0  = (const float*)d_in[2];
  const float* p1  = (const float*)d_in[3];
  const float* p2  = (const float*)d_in[4];
  const float* p3  = (const float*)d_in[5];
  float* out = (float*)d_out;
  float2* st = (float2*)d_ws;                           // 8 MB state
  float* tbl = (float*)((char*)d_ws + (8u<<20));        // 600-float gate table

  k_setup<<<1, 64, 0, stream>>>(p0, p1, p2, p3, tbl, out);
  k_p1<<<512, 512, 0, stream>>>(xre, xim, tbl, st);
  k_p2<<<512, 512, 0, stream>>>(tbl, st);
  k_p4<<<512, 512, 0, stream>>>(tbl, st, out);
}

// Round 10
// 113.984 us; speedup vs baseline: 1.0063x; 1.0063x over previous
//
#include <hip/hip_runtime.h>

// Quantum conv circuit, 16 qubits, batch 16.
// Round 10: barrier-elimination. Each wave holds 8 of the 11 tile bits (2 reg + 6 lane);
//   gates on lane bits applied directly via __shfl_xor (lgate) — no repositioning, no
//   barriers. Only the 3 wave bits need ONE LDS exchange per kernel (28 barriers -> 3).
//   sigma1a/2/3 CNOTs = in-wave cond-swaps / reg swaps; sigma1b stays in the P4 gather.
// 512 blocks x 512 threads, 4 amps/thread, 11-bit tiles. st = float2[16][65536] at d_ws;
// tbl (600 floats) at d_ws + 8MB. Bit convention: wire w <-> flat bit p = 15-w.
// Gate index: L1d0(p)=15-p, L1d1(p)=16+(15-p), L2d0(p)=32+(15-p)/2, L2d1(p)=40+(15-p)/2,
//             L3d0(p)=48+(15-p)/4, L3d1(p)=52+(15-p)/4, L4d0(p)=56+(15-p)/8, L4d1(p)=58+(15-p)/8.

#define DEV __device__ __forceinline__
#define TBL(i) (tbl + (i)*8)

__device__ static const unsigned char G_CP[60] = {
  15,14,13,12,11,10,9,8,7,6,5,4,3,2,1,0,
  15,14,13,12,11,10,9,8,7,6,5,4,3,2,1,0,
  15,13,11,9,7,5,3,1,
  15,13,11,9,7,5,3,1,
  15,11,7,3,
  15,11,7,3,
  15,7,
  15,7
};
__device__ static const unsigned char G_CQ[60] = {
  14,13,12,11,10,9,8,7,6,5,4,3,2,1,0,15,
  14,13,12,11,10,9,8,7,6,5,4,3,2,1,0,15,
  13,11,9,7,5,3,1,15,
  13,11,9,7,5,3,1,15,
  11,7,3,15,
  11,7,3,15,
  7,15,
  7,15
};

DEV float2 F2(float x, float y){ float2 r; r.x = x; r.y = y; return r; }
DEV float2 cmulf(float2 a, float2 b){ return F2(a.x*b.x - a.y*b.y, a.x*b.y + a.y*b.x); }
DEV int swz(int j){ return j ^ ((j>>4)&15) ^ ((j>>8)&15); }

// gate on register slot bit SB (free)
template<int SB>
DEV void gate4(float2* a, const float* __restrict__ g){
  float u00r=g[0],u00i=g[1],u01r=g[2],u01i=g[3],u10r=g[4],u10i=g[5],u11r=g[6],u11i=g[7];
  #pragma unroll
  for (int m=0;m<2;m++){
    int i0 = (SB==0) ? (m<<1) : m;
    int i1 = i0 | (1<<SB);
    float2 x0=a[i0], x1=a[i1];
    a[i0] = F2(u00r*x0.x - u00i*x0.y + u01r*x1.x - u01i*x1.y,
               u00r*x0.y + u00i*x0.x + u01r*x1.y + u01i*x1.x);
    a[i1] = F2(u10r*x0.x - u10i*x0.y + u11r*x1.x - u11i*x1.y,
               u10r*x0.y + u10i*x0.x + u11r*x1.y + u11i*x1.x);
  }
}

// gate on LANE bit (partner via shfl_xor; no barrier). h=0: new = u00*self + u01*p;
// h=1: new = u10*p + u11*self.
DEV void lgate(float2* a, const float* __restrict__ g, int mask, int lane){
  bool h = (lane & mask) != 0;
  float c0r = h ? g[4] : g[0], c0i = h ? g[5] : g[1];
  float c1r = h ? g[6] : g[2], c1i = h ? g[7] : g[3];
  #pragma unroll
  for (int s=0;s<4;s++){
    float px = __shfl_xor(a[s].x, mask);
    float py = __shfl_xor(a[s].y, mask);
    float x0x = h ? px : a[s].x, x0y = h ? py : a[s].y;
    float x1x = h ? a[s].x : px, x1y = h ? a[s].y : py;
    a[s] = F2(c0r*x0x - c0i*x0y + c1r*x1x - c1i*x1y,
              c0r*x0y + c0i*x0x + c1r*x1y + c1i*x1x);
  }
}

// CNOT with control lane-bit cmask, target lane-bit tmask (in-wave cond pair-swap)
DEV void cswap(float2* a, int cmask, int tmask, int lane){
  bool c = (lane & cmask) != 0;
  #pragma unroll
  for (int s=0;s<4;s++){
    float px = __shfl_xor(a[s].x, tmask);
    float py = __shfl_xor(a[s].y, tmask);
    if (c){ a[s].x = px; a[s].y = py; }
  }
}

// RZZ round, couplings [C0,C0+N). Ib = true index with the two reg bits zeroed.
template<int C0,int N,unsigned M0,unsigned M1>
DEV void diag4(float2* a, const float* __restrict__ tbl, unsigned Ib){
  const unsigned regmask = M0|M1;
  float2 F0 = F2(1.f, 0.f);
  #pragma unroll
  for (int k=0;k<N;k++){
    const int p = G_CP[C0+k], q = G_CQ[C0+k];
    if ( !(((1u<<p)|(1u<<q)) & regmask) ){
      float c = tbl[480 + 2*(C0+k)], s = tbl[481 + 2*(C0+k)];
      unsigned x = ((Ib>>p) ^ (Ib>>q)) & 1u;
      F0 = cmulf(F0, F2(c, x ? s : -s));
    }
  }
  #pragma unroll
  for (int r=0;r<4;r++){
    unsigned Ir = Ib ^ ((r&1)?M0:0u) ^ ((r&2)?M1:0u);
    float2 ph = F0;
    #pragma unroll
    for (int k=0;k<N;k++){
      const int p = G_CP[C0+k], q = G_CQ[C0+k];
      if ( ((1u<<p)|(1u<<q)) & regmask ){
        float c = tbl[480 + 2*(C0+k)], s = tbl[481 + 2*(C0+k)];
        unsigned x = ((Ir>>p) ^ (Ir>>q)) & 1u;
        ph = cmulf(ph, F2(c, x ? s : -s));
      }
    }
    a[r] = cmulf(a[r], ph);
  }
}

// ---- global index maps (verbatim r9, verified) ----
DEV unsigned Ib2(int j, int o){ return (unsigned)((j&63) | (o<<6) | ((j>>6)<<11)); }
DEV unsigned Ic(int j, int o){
  return (unsigned)( ((j&1)<<1) | (((j>>1)&1)<<3) | (((j>>2)&1)<<5)
       | (((j>>3)&63)<<6) | (((j>>9)&1)<<13) | (((j>>10)&1)<<15)
       | (o&1) | (((o>>1)&1)<<2) | (((o>>2)&1)<<4) | (((o>>3)&1)<<12) | (((o>>4)&1)<<14) );
}
DEV unsigned s1b(unsigned I){ return I ^ ((I & 0xA02Au) >> 1); }

// ---------- setup ----------
__global__ void k_setup(const float* __restrict__ p0, const float* __restrict__ p1,
                        const float* __restrict__ p2, const float* __restrict__ p3,
                        float* __restrict__ tbl, float* __restrict__ out){
  int g = threadIdx.x;
  if (g < 16) out[g] = 0.f;
  if (g >= 60) return;
  int d, j, n; const float* P;
  if (g < 32)      { n=16; d=(g>>4)&1; j=g&15; P=p0; }
  else if (g < 48) { n=8;  d=(g>>3)&1; j=g&7;  P=p1; }
  else if (g < 56) { n=4;  d=(g>>2)&1; j=g&3;  P=p2; }
  else             { n=2;  d=(g>>1)&1; j=g&1;  P=p3; }
  int base = 4*j + 4*n*d;
  double th0 = P[base+0], th1 = P[base+1], th2 = P[base+2], th3 = P[base+3];
  double c0 = cos(th0*0.5), s0 = sin(th0*0.5);
  double ca = cos(th1*0.5), sa = sin(th1*0.5);
  double c2 = cos(th2*0.5), s2 = sin(th2*0.5);
  double B00r =  ca*c0, B00i = -sa*c0;
  double B01r = -sa*s0, B01i = -ca*s0;
  double B10r =  sa*s0, B10i = -ca*s0;
  double B11r =  ca*c0, B11i =  sa*c0;
  float* o = tbl + g*8;
  o[0]=(float)(c2*B00r + s2*B10i); o[1]=(float)(c2*B00i - s2*B10r);
  o[2]=(float)(c2*B01r + s2*B11i); o[3]=(float)(c2*B01i - s2*B11r);
  o[4]=(float)(s2*B00i + c2*B10r); o[5]=(float)(-s2*B00r + c2*B10i);
  o[6]=(float)(s2*B01i + c2*B11r); o[7]=(float)(-s2*B01r + c2*B11i);
  tbl[480 + 2*g] = (float)cos(th3*0.5);
  tbl[481 + 2*g] = (float)sin(th3*0.5);
}

// ======== pass 1: L1d0 g0..g10. inner j = g0..10, outer o = g11..15 ========
// Layout A: reg=(j0,j1), lane=(j2..j7), wave=(j8,j9,j10). One LDS exchange ->
// Layout B: reg=(j8,j9), lane=(j0..j4,j10), wave=(j5,j6,j7).
__global__ __launch_bounds__(512, 4)
void k_p1(const float* __restrict__ xre, const float* __restrict__ xim,
          const float* __restrict__ tbl, float2* __restrict__ st){
  const int t = threadIdx.x, lane = t & 63, wv = t >> 6;
  const int batch = blockIdx.x >> 5, o = blockIdx.x & 31;
  const unsigned hi = ((unsigned)batch<<16) | ((unsigned)o<<11);
  __shared__ float2 lds[2048];
  float2 a[4];
  { // load layout A: jA = s | (t<<2)
    unsigned base = hi | ((unsigned)t<<2);
    float4 re = *(const float4*)(xre + base);
    float4 im = *(const float4*)(xim + base);
    a[0]=F2(re.x,im.x); a[1]=F2(re.y,im.y); a[2]=F2(re.z,im.z); a[3]=F2(re.w,im.w);
  }
  gate4<0>(a, TBL(15)); gate4<1>(a, TBL(14));            // g0,g1 (reg)
  lgate(a, TBL(13), 1, lane);  lgate(a, TBL(12), 2, lane);   // g2,g3
  lgate(a, TBL(11), 4, lane);  lgate(a, TBL(10), 8, lane);   // g4,g5
  lgate(a, TBL(9), 16, lane);  lgate(a, TBL(8), 32, lane);   // g6,g7
  #pragma unroll
  for (int s=0;s<4;s++) lds[swz((t<<2)|s)] = a[s];
  __syncthreads();
  #pragma unroll
  for (int s=0;s<4;s++){
    int jB = (lane&31) | (wv<<5) | (s<<8) | ((lane>>5)<<10);
    a[s] = lds[swz(jB)];
  }
  gate4<0>(a, TBL(7)); gate4<1>(a, TBL(6));              // g8,g9 (reg)
  lgate(a, TBL(5), 32, lane);                            // g10 (lane bit5)
  #pragma unroll
  for (int s=0;s<4;s++){
    int jB = (lane&31) | (wv<<5) | (s<<8) | ((lane>>5)<<10);
    st[hi | (unsigned)jB] = a[s];
  }
}

// ======== pass 2: L1d0 g11..15, D0, L1d1 {g0..5, g11..15}. outer o = g6..g10 ========
// j0..j5 = g0..g5, j6..j10 = g11..g15.
// Layout A: reg=(j10,j9)=(g15,g14); lane bits0-2=(j8,j7,j6)=(g13,g12,g11),
//           bits3-5=(j0,j1,j2)=(g0,g1,g2); wave=(j3,j4,j5)=(g3,g4,g5).
// Layout B: reg=(j3,j4)=(g3,g4); lane=(j0,j1,j2,j5,j9,j10); wave=(j6,j7,j8).
__global__ __launch_bounds__(512, 4)
void k_p2(const float* __restrict__ tbl, float2* __restrict__ st){
  const int t = threadIdx.x, lane = t & 63, wv = t >> 6;
  const int batch = blockIdx.x >> 5, o = blockIdx.x & 31;
  const unsigned bb = (unsigned)batch<<16;
  __shared__ float2 lds[2048];
  float2 a[4];
  int jA0 = ((lane&1)<<8) | (((lane>>1)&1)<<7) | (((lane>>2)&1)<<6)
          | (((lane>>3)&1)<<0) | (((lane>>4)&1)<<1) | (((lane>>5)&1)<<2) | (wv<<3);
  #pragma unroll
  for (int s=0;s<4;s++){
    int jA = jA0 | ((s&1)<<10) | (((s>>1)&1)<<9);
    a[s] = st[bb | Ib2(jA, o)];
  }
  gate4<0>(a, TBL(0)); gate4<1>(a, TBL(1));              // L1d0 g15,g14 (reg)
  lgate(a, TBL(2), 1, lane); lgate(a, TBL(3), 2, lane); lgate(a, TBL(4), 4, lane); // g13,g12,g11
  diag4<0,16, (1u<<15),(1u<<14)>(a, tbl, Ib2(jA0, o));   // D0
  lgate(a, TBL(20), 4, lane); lgate(a, TBL(19), 2, lane); lgate(a, TBL(18), 1, lane); // L1d1 g11,g12,g13
  gate4<1>(a, TBL(17)); gate4<0>(a, TBL(16));            // L1d1 g14,g15
  lgate(a, TBL(31), 8, lane); lgate(a, TBL(30), 16, lane); lgate(a, TBL(29), 32, lane); // g0,g1,g2
  #pragma unroll
  for (int s=0;s<4;s++){
    int jA = jA0 | ((s&1)<<10) | (((s>>1)&1)<<9);
    lds[swz(jA)] = a[s];
  }
  __syncthreads();
  int jB0 = (lane&7) | (((lane>>3)&1)<<5) | (wv<<6)
          | (((lane>>4)&1)<<9) | (((lane>>5)&1)<<10);
  #pragma unroll
  for (int s=0;s<4;s++){
    int jB = jB0 | ((s&1)<<3) | (((s>>1)&1)<<4);
    a[s] = lds[swz(jB)];
  }
  gate4<0>(a, TBL(28)); gate4<1>(a, TBL(27));            // L1d1 g3,g4 (reg)
  lgate(a, TBL(26), 8, lane);                            // L1d1 g5 (lane bit3)
  #pragma unroll
  for (int s=0;s<4;s++){
    int jB = jB0 | ((s&1)<<3) | (((s>>1)&1)<<4);
    st[bb | Ib2(jB, o)] = a[s];
  }
}

// ======== pass 4: s1b-gather, L1d1 g6..10, D1, s1a, L2..L4, measure ========
// j-map (Ic): j0..j10 -> g{1,3,5,6,7,8,9,10,11,13,15}; outer o -> g{0,2,4,12,14}.
// Layout A: reg=(j3,j4)=(g6,g7); lane bits0-2=(j0,j1,j2)=(g1,g3,g5),
//           bits3-5=(j5,j6,j7)=(g8,g9,g10); wave=(j8,j9,j10)=(g11,g13,g15).
// Layout B: reg=(j0,j1)=(g1,g3); lane=(j2,j4,j6,j8,j9,j10)=(g5,g7,g9,g11,g13,g15);
//           wave=(j3,j5,j7)=(g6,g8,g10).
__global__ __launch_bounds__(512, 4)
void k_p4(const float* __restrict__ tbl, float2* __restrict__ st, float* __restrict__ out){
  const int t = threadIdx.x, lane = t & 63, wv = t >> 6;
  const int batch = blockIdx.x >> 5, o = blockIdx.x & 31;
  const unsigned bb = (unsigned)batch<<16;
  __shared__ float2 lds[2048];
  __shared__ float red[8];
  float2 a[4];
  int jA0 = (lane&7) | (((lane>>3)&7)<<5) | (wv<<8);
  #pragma unroll
  for (int s=0;s<4;s++){
    int jA = jA0 | ((s&1)<<3) | (((s>>1)&1)<<4);
    a[s] = st[bb | s1b(Ic(jA, o))];
  }
  gate4<0>(a, TBL(25)); gate4<1>(a, TBL(24));            // L1d1 g6,g7 (reg)
  lgate(a, TBL(23), 8, lane); lgate(a, TBL(22), 16, lane); lgate(a, TBL(21), 32, lane); // g8,g9,g10
  diag4<16,16, (1u<<6),(1u<<7)>(a, tbl, s1b(Ic(jA0, o))); // D1 (index = amplitude's own)
  // sigma1a: (g11->g10): ctrl = wave bit0, tgt = lane bit5 (wave-uniform swap)
  if (wv & 1){
    #pragma unroll
    for (int s=0;s<4;s++){ a[s].x = __shfl_xor(a[s].x, 32); a[s].y = __shfl_xor(a[s].y, 32); }
  }
  cswap(a, 16, 8, lane);                                 // (g9->g8)
  { float2 tmp=a[2]; a[2]=a[3]; a[3]=tmp; }              // (g7->g6): reg ctrl s1, tgt s0
  #pragma unroll
  for (int s=0;s<4;s++){
    int jA = jA0 | ((s&1)<<3) | (((s>>1)&1)<<4);
    lds[swz(jA)] = a[s];
  }
  __syncthreads();
  int jB0 = ((lane&1)<<2) | (((lane>>1)&1)<<4) | (((lane>>2)&1)<<6)
          | (((lane>>3)&1)<<8) | (((lane>>4)&1)<<9) | (((lane>>5)&1)<<10)
          | ((wv&1)<<3) | (((wv>>1)&1)<<5) | (((wv>>2)&1)<<7);
  #pragma unroll
  for (int s=0;s<4;s++) a[s] = lds[swz(jB0 | (s&1) | (((s>>1)&1)<<1))];
  const unsigned IbB = Ic(jB0, o);
  // L2d0: g1,g3 (reg); g5,g7,g9,g11,g13,g15 (lane bits 0..5)
  gate4<0>(a, TBL(39)); gate4<1>(a, TBL(38));
  lgate(a, TBL(37), 1, lane); lgate(a, TBL(36), 2, lane); lgate(a, TBL(35), 4, lane);
  lgate(a, TBL(34), 8, lane); lgate(a, TBL(33), 16, lane); lgate(a, TBL(32), 32, lane);
  diag4<32,8, 2u,8u>(a, tbl, IbB);                       // D2_0
  // L2d1
  gate4<0>(a, TBL(47)); gate4<1>(a, TBL(46));
  lgate(a, TBL(45), 1, lane); lgate(a, TBL(44), 2, lane); lgate(a, TBL(43), 4, lane);
  lgate(a, TBL(42), 8, lane); lgate(a, TBL(41), 16, lane); lgate(a, TBL(40), 32, lane);
  diag4<40,8, 2u,8u>(a, tbl, IbB);                       // D2_1
  // sigma2: (g15->g13),(g11->g9),(g7->g5) in-wave; (g3->g1) reg
  cswap(a, 32, 16, lane); cswap(a, 8, 4, lane); cswap(a, 2, 1, lane);
  { float2 tmp=a[2]; a[2]=a[3]; a[3]=tmp; }
  // L3d0 {g15,g11,g7,g3}
  lgate(a, TBL(48), 32, lane); lgate(a, TBL(49), 8, lane); lgate(a, TBL(50), 2, lane);
  gate4<1>(a, TBL(51));
  diag4<48,4, 2u,8u>(a, tbl, IbB);                       // D3_0
  // L3d1
  lgate(a, TBL(52), 32, lane); lgate(a, TBL(53), 8, lane); lgate(a, TBL(54), 2, lane);
  gate4<1>(a, TBL(55));
  diag4<52,4, 2u,8u>(a, tbl, IbB);                       // D3_1
  // sigma3: (g15->g11) in-wave; (g7->g3): ctrl lane bit1, tgt reg s1
  cswap(a, 32, 8, lane);
  if (lane & 2){
    float2 t0=a[0]; a[0]=a[2]; a[2]=t0;
    float2 t1=a[1]; a[1]=a[3]; a[3]=t1;
  }
  // L4d0 {g15,g7}, D4_0, L4d1 g15
  lgate(a, TBL(56), 32, lane); lgate(a, TBL(57), 2, lane);
  diag4<56,2, 2u,8u>(a, tbl, IbB);
  lgate(a, TBL(58), 32, lane);
  // sigma4, D4_1, L4d1(g7) dropped: invariant for the g15 marginal.
  // measure Z on g15 = lane bit5
  float sl = 0.f;
  #pragma unroll
  for (int s=0;s<4;s++) sl += a[s].x*a[s].x + a[s].y*a[s].y;
  float sg = (lane & 32) ? -sl : sl;
  #pragma unroll
  for (int off=32; off>0; off>>=1) sg += __shfl_down(sg, off);
  __syncthreads();
  if ((t & 63) == 0) red[wv] = sg;
  __syncthreads();
  if (t == 0){
    float tot = 0.f;
    #pragma unroll
    for (int w=0; w<8; w++) tot += red[w];
    atomicAdd(out + batch, tot);
  }
}

extern "C" void kernel_launch(void* const* d_in, const int* in_sizes, int n_in,
                              void* d_out, int out_size, void* d_ws, size_t ws_size,
                              hipStream_t stream) {
  const float* xre = (const float*)d_in[0];
  const float* xim = (const float*)d_in[1];
  const float* p0  = (const float*)d_in[2];
  const float* p1  = (const float*)d_in[3];
  const float* p2  = (const float*)d_in[4];
  const float* p3  = (const float*)d_in[5];
  float* out = (float*)d_out;
  float2* st = (float2*)d_ws;                           // 8 MB state
  float* tbl = (float*)((char*)d_ws + (8u<<20));        // 600-float gate table

  k_setup<<<1, 64, 0, stream>>>(p0, p1, p2, p3, tbl, out);
  k_p1<<<512, 512, 0, stream>>>(xre, xim, tbl, st);
  k_p2<<<512, 512, 0, stream>>>(tbl, st);
  k_p4<<<512, 512, 0, stream>>>(tbl, st, out);
}